// Round 17
// baseline (82.178 us; speedup 1.0000x reference)
//
#include <hip/hip_runtime.h>

#define NN 5000
#define NF 4
#define NT 12
#define NC 600
#define NCP 640   // padded d-extent (zero pad -> r=0, no predication)
#define NE 160000
#define FT 48   // NF*NT
#define LOG2E 1.4426950408889634f

typedef float v2f __attribute__((ext_vector_type(2)));

// ws layout (float offsets):
//   cnt   [0,     5000)    int   (zeroed by k_init)
//   base  [5000, 10001)    int   (pad to 10008)
//   rank  [10008,170008)   int
//   epak  [170008,490008)  int2 (src, w-bits) per bucketed edge
//   dis   [490008,495008)
//   agg   [495008,735008)
//   tabG  [735008,749100)  packed PADDED tables (zeroed by k_init):
//     mz4   [0,2560)       float4[640] (LOG2E-scaled)
//     mh4   [2560,5120)    float4[640] (2*LOG2E-scaled)
//     bzh   [5120,6400)    float2[640] (betaz,betah)
//     wt    [6400,14080)   float4[3][640]: wt[q][d][j] = Whead[4q+j][d]
//     probs [14080,14092)

// zero cnt (5000 words) and tabG (14092 words)
__global__ void k_init(int* __restrict__ cnt, float* __restrict__ tabG) {
    int i = blockIdx.x * blockDim.x + threadIdx.x;
    if (i < 5000) cnt[i] = 0;
    else if (i < 19092) tabG[i - 5000] = 0.f;
}

// Fused: blocks [0,625) rank histogram (int atomic only);
//        blocks [625,...) weight composition into tabG (independent work).
#define CNT_BLOCKS 625
#define WB_WAVES 6132   // 6000 table + 12 probs + 120 wt-repack
__global__ __launch_bounds__(256) void k_count(
        const int* __restrict__ ei,
        int* __restrict__ cnt, int* __restrict__ rank,
        const float* __restrict__ Wz, const float* __restrict__ bz,
        const float* __restrict__ Wh, const float* __restrict__ bh,
        const float* __restrict__ Wlz, const float* __restrict__ blz,
        const float* __restrict__ Wlh, const float* __restrict__ blh,
        const float* __restrict__ att, const float* __restrict__ Whead,
        float* __restrict__ tabG) {
    int bid = blockIdx.x;
    int tid = threadIdx.x;
    if (bid < CNT_BLOCKS) {
        int e = bid * 256 + tid;
        if (e < NE) rank[e] = atomicAdd(&cnt[ei[NE + e]], 1);
        return;
    }
    int wid = (bid - CNT_BLOCKS) * 4 + (tid >> 6);
    int lane = tid & 63;
    if (wid >= WB_WAVES) return;

    if (wid < 6000) {
        const float* va;
        const float* vb;
        float scale, bias = 0.f;
        if (wid < 2400) {
            int f = wid / NC, d = wid % NC;
            va = Wz + f * NC; vb = Wlz + d * (2 * NC); scale = LOG2E;
        } else if (wid < 4800) {
            int j = wid - 2400;
            int f = j / NC, d = j % NC;
            va = Wh + f * NC; vb = Wlh + d * (2 * NC); scale = 2.0f * LOG2E;
        } else if (wid < 5400) {
            int d = wid - 4800;
            va = bz; vb = Wlz + d * (2 * NC); scale = LOG2E; bias = blz[d];
        } else {
            int d = wid - 5400;
            va = bh; vb = Wlh + d * (2 * NC); scale = 2.0f * LOG2E; bias = blh[d];
        }
        float s = 0.f;
        for (int c = lane; c < NC; c += 64) s = fmaf(va[c], vb[c], s);
#pragma unroll
        for (int off = 32; off > 0; off >>= 1) s += __shfl_down(s, off, 64);
        if (lane == 0) {
            float r = scale * (bias + s);
            if (wid < 2400) {
                int f = wid / NC, d = wid % NC;
                tabG[d * 4 + f] = r;
            } else if (wid < 4800) {
                int j = wid - 2400;
                int f = j / NC, d = j % NC;
                tabG[2560 + d * 4 + f] = r;
            } else if (wid < 5400) {
                tabG[5120 + (wid - 4800) * 2] = r;
            } else {
                tabG[5120 + (wid - 5400) * 2 + 1] = r;
            }
        }
    } else if (wid < 6012) {
        if (lane == 0) {
            int t = wid - 6000;
            float m = att[0];
            for (int k = 1; k < NT; ++k) m = fmaxf(m, att[k]);
            float ssum = 0.f;
            for (int k = 0; k < NT; ++k) ssum += __expf(att[k] - m);
            tabG[14080 + t] = __expf(att[t] - m) / ssum;
        }
    } else {
        int i = (wid - 6012) * 64 + lane;   // [0,7680)
        if (i < 7680) {
            int j = i & 3;
            int rest = i >> 2;          // [0,1920)
            int d = rest % NCP, q = rest / NCP;
            float v = (d < NC) ? Whead[(4 * q + j) * NC + d] : 0.f;
            tabG[6400 + i] = v;
        }
    }
}

// single-block exclusive scan of cnt -> base
#define SCAN_CHUNK 20
__global__ __launch_bounds__(256) void k_scan(const int* __restrict__ cnt,
                                              int* __restrict__ base) {
    __shared__ int part[256];
    int t = threadIdx.x;
    int start = t * SCAN_CHUNK;
    int s = 0;
#pragma unroll
    for (int k = 0; k < SCAN_CHUNK; ++k) {
        int idx = start + k;
        if (idx < NN) s += cnt[idx];
    }
    part[t] = s;
    __syncthreads();
    for (int off = 1; off < 256; off <<= 1) {
        int v = (t >= off) ? part[t - off] : 0;
        __syncthreads();
        part[t] += v;
        __syncthreads();
    }
    int running = (t == 0) ? 0 : part[t - 1];
#pragma unroll
    for (int k = 0; k < SCAN_CHUNK; ++k) {
        int idx = start + k;
        if (idx < NN) {
            base[idx] = running;
            running += cnt[idx];
        }
    }
    if (t == 255) base[NN] = part[255];
}

// deterministic-position scatter of packed (src, weight): one 8B store
__global__ void k_scatter(const int* __restrict__ ei, const float* __restrict__ w,
                          const int* __restrict__ base, const int* __restrict__ rank,
                          int2* __restrict__ epak) {
    int e = blockIdx.x * blockDim.x + threadIdx.x;
    if (e < NE) {
        int2 p; p.x = ei[e]; p.y = __float_as_int(w[e]);
        epak[base[ei[NE + e]] + rank[e]] = p;
    }
}

// per-node degree from packed edges (sequential reads), dis = rsqrt(1+deg)
__global__ __launch_bounds__(64) void k_deg_dis(const int2* __restrict__ epak,
                                                const int* __restrict__ base,
                                                float* __restrict__ dis) {
    int n = blockIdx.x;
    int lane = threadIdx.x;
    int b0 = base[n], b1 = base[n + 1];
    float s = 0.f;
    for (int j = b0 + lane; j < b1; j += 64) s += __int_as_float(epak[j].y);
#pragma unroll
    for (int off = 32; off > 0; off >>= 1) s += __shfl_down(s, off, 64);
    if (lane == 0) dis[n] = rsqrtf(1.0f + s);
}

// one 64-thread block per node, LANE-PARALLEL edge prefetch:
// lane j loads epak[b0+j] (coalesced, 64 edges/inst) and its own
// nu = dis[src]*w; the broadcast loop then issues all x-row loads
// back-to-back (register shuffles carry src/nu -> ~32 loads in flight).
__global__ __launch_bounds__(64) void k_gather(
        const float* __restrict__ x, const float* __restrict__ dis,
        const int2* __restrict__ epak, const int* __restrict__ base,
        float* __restrict__ agg) {
    int n = blockIdx.x;
    int lane = threadIdx.x;
    int b0 = base[n], b1 = base[n + 1];
    float dn = dis[n];
    float acc = 0.f;
    if (lane < FT) acc = dn * x[n * FT + lane];

    for (int jb = b0; jb < b1; jb += 64) {
        int m = b1 - jb; if (m > 64) m = 64;
        int src = 0; float nu = 0.f;
        if (jb + lane < b1) {
            int2 p = epak[jb + lane];
            src = p.x;
            nu = dis[p.x] * __int_as_float(p.y);
        }
        for (int j = 0; j < m; ++j) {
            int s = __shfl(src, j, 64);
            float v = __shfl(nu, j, 64);
            if (lane < FT) acc = fmaf(v, x[s * FT + lane], acc);
        }
    }
    if (lane < FT) agg[n * FT + lane] = dn * acc;
}

// Gate + attention + head. 1250 blocks x 4 waves; wave = node.
// n wave-uniform via readfirstlane -> agg row + probs live in SGPRs;
// lb(256,4) caps VGPR at 64 (demand ~50 with scalar A2 -> no spill, 16 w/CU).
__global__ __launch_bounds__(256, 4) void k_main(
        const float* __restrict__ agg, const float* __restrict__ tabG,
        const float* __restrict__ bhead, float* __restrict__ out) {
    __shared__ float red[4][NT][16];
    int tid = threadIdx.x;
    int wid = __builtin_amdgcn_readfirstlane(tid >> 6);
    int lane = tid & 63;
    int n = blockIdx.x * 4 + wid;   // uniform

    const float4* mz4 = (const float4*)tabG;
    const float4* mh4 = (const float4*)(tabG + 2560);
    const float2* bzh = (const float2*)(tabG + 5120);
    const float4* wt4 = (const float4*)(tabG + 6400);   // [q*640 + d]

    // wave-uniform agg row -> scalar loads (SGPR-resident)
    const v2f* ag2 = (const v2f*)(agg + n * FT);
    v2f A2[24];
#pragma unroll
    for (int i = 0; i < 24; ++i) A2[i] = ag2[i];

    v2f pp[6];
#pragma unroll
    for (int tp = 0; tp < 6; ++tp) { pp[tp].x = tabG[14080 + 2 * tp]; pp[tp].y = tabG[14080 + 2 * tp + 1]; }

    float outp[NT];
#pragma unroll
    for (int t = 0; t < NT; ++t) outp[t] = 0.f;

#pragma unroll
    for (int it = 0; it < 10; ++it) {
        int dd = it * 64 + lane;   // < 640, pad rows are zero -> r = 0

        float4 mzv = mz4[dd];
        float4 mhv = mh4[dd];
        float2 bb = bzh[dd];

        v2f hacc; hacc.x = 0.f; hacc.y = 0.f;
#pragma unroll
        for (int tp = 0; tp < 6; ++tp) {
            v2f u; u.x = bb.x; u.y = bb.x;
            v2f v; v.x = bb.y; v.y = bb.y;
            u += A2[0 * 6 + tp] * mzv.x;
            u += A2[1 * 6 + tp] * mzv.y;
            u += A2[2 * 6 + tp] * mzv.z;
            u += A2[3 * 6 + tp] * mzv.w;
            v += A2[0 * 6 + tp] * mhv.x;
            v += A2[1 * 6 + tp] * mhv.y;
            v += A2[2 * 6 + tp] * mhv.z;
            v += A2[3 * 6 + tp] * mhv.w;
            v2f eu; eu.x = exp2f(u.x); eu.y = exp2f(u.y);
            v2f ev; ev.x = exp2f(v.x); ev.y = exp2f(v.y);
            v2f den = (eu + 1.f) * (ev + 1.f);
            v2f rd; rd.x = __builtin_amdgcn_rcpf(den.x); rd.y = __builtin_amdgcn_rcpf(den.y);
            v2f num = pp[tp] * (ev - 1.f);
            hacc += num * rd;
        }
        float r = fmaxf(hacc.x + hacc.y, 0.f);

        float4 w0 = wt4[0 * NCP + dd], w1 = wt4[1 * NCP + dd], w2 = wt4[2 * NCP + dd];
        outp[0]  = fmaf(r, w0.x, outp[0]);   outp[1]  = fmaf(r, w0.y, outp[1]);
        outp[2]  = fmaf(r, w0.z, outp[2]);   outp[3]  = fmaf(r, w0.w, outp[3]);
        outp[4]  = fmaf(r, w1.x, outp[4]);   outp[5]  = fmaf(r, w1.y, outp[5]);
        outp[6]  = fmaf(r, w1.z, outp[6]);   outp[7]  = fmaf(r, w1.w, outp[7]);
        outp[8]  = fmaf(r, w2.x, outp[8]);   outp[9]  = fmaf(r, w2.y, outp[9]);
        outp[10] = fmaf(r, w2.z, outp[10]);  outp[11] = fmaf(r, w2.w, outp[11]);
    }

    // 2-step shuffle then 16-wide LDS transpose reduce (wave-private)
#pragma unroll
    for (int t = 0; t < NT; ++t) {
        float v = outp[t];
        v += __shfl_xor(v, 32, 64);
        v += __shfl_xor(v, 16, 64);
        if (lane < 16) red[wid][t][lane] = v;
    }
    if (lane < NT) {
        const float4* row = (const float4*)red[wid][lane];
        float4 a = row[0], b = row[1], c = row[2], d = row[3];
        float s = ((a.x + a.y) + (a.z + a.w)) + ((b.x + b.y) + (b.z + b.w))
                + ((c.x + c.y) + (c.z + c.w)) + ((d.x + d.y) + (d.z + d.w));
        out[n * NT + lane] = s + bhead[lane];
    }
}

extern "C" void kernel_launch(void* const* d_in, const int* in_sizes, int n_in,
                              void* d_out, int out_size, void* d_ws, size_t ws_size,
                              hipStream_t stream) {
    const float* x     = (const float*)d_in[0];
    const int*   ei    = (const int*)d_in[1];
    const float* ea    = (const float*)d_in[2];
    const float* Wz    = (const float*)d_in[3];
    const float* bz    = (const float*)d_in[4];
    const float* Wh    = (const float*)d_in[7];
    const float* bh    = (const float*)d_in[8];
    const float* Wlz   = (const float*)d_in[9];
    const float* blz   = (const float*)d_in[10];
    const float* Wlh   = (const float*)d_in[13];
    const float* blh   = (const float*)d_in[14];
    const float* att   = (const float*)d_in[15];
    const float* Whead = (const float*)d_in[16];
    const float* bhead = (const float*)d_in[17];
    float* out = (float*)d_out;

    float* ws   = (float*)d_ws;
    int*   cnt  = (int*)ws;                 // [0,5000)
    int*   base = (int*)(ws + 5000);        // [5000,10008)
    int*   rank = (int*)(ws + 10008);
    int2*  epak = (int2*)(ws + 170008);
    float* dis  = ws + 490008;
    float* agg  = ws + 495008;
    float* tabG = ws + 735008;

    k_init<<<(19092 + 255) / 256, 256, 0, stream>>>(cnt, tabG);
    k_count<<<CNT_BLOCKS + (WB_WAVES + 3) / 4, 256, 0, stream>>>(
        ei, cnt, rank,
        Wz, bz, Wh, bh, Wlz, blz, Wlh, blh, att, Whead, tabG);
    k_scan<<<1, 256, 0, stream>>>(cnt, base);
    k_scatter<<<(NE + 255) / 256, 256, 0, stream>>>(ei, ea, base, rank, epak);
    k_deg_dis<<<NN, 64, 0, stream>>>(epak, base, dis);
    k_gather<<<NN, 64, 0, stream>>>(x, dis, epak, base, agg);
    k_main<<<NN / 4, 256, 0, stream>>>(agg, tabG, bhead, out);
}

// Round 18
// 81.483 us; speedup vs baseline: 1.0085x; 1.0085x over previous
//
#include <hip/hip_runtime.h>

#define NN 5000
#define NF 4
#define NT 12
#define NC 600
#define NCP 640   // padded d-extent (zero pad -> r=0, no predication)
#define NE 160000
#define FT 48   // NF*NT
#define LOG2E 1.4426950408889634f
#define WSCALE 67108864.0f         // 2^26 fixed-point scale for weight sums
#define MASK44 ((1ULL << 44) - 1)

typedef float v2f __attribute__((ext_vector_type(2)));
typedef unsigned long long u64;

// ws layout (float offsets):
//   cnt64 [0,    10000)    u64[5000]: (count<<44)|wsum_fp26  (zeroed by k_init)
//   base  [10000,15001)    int (pad to 15008)
//   rank  [15008,175008)   int
//   epak  [175008,495008)  int2 (src, w-bits) per bucketed edge
//   dis   [495008,500008)
//   agg   [500008,740008)
//   tabG  [740008,754100)  packed PADDED tables (zeroed by k_init):
//     mz4   [0,2560)       float4[640] (LOG2E-scaled)
//     mh4   [2560,5120)    float4[640] (2*LOG2E-scaled)
//     bzh   [5120,6400)    float2[640] (betaz,betah)
//     wt    [6400,14080)   float4[3][640]: wt[q][d][j] = Whead[4q+j][d]
//     probs [14080,14092)

// zero cnt64 (10000 words) and tabG (14092 words)
__global__ void k_init(int* __restrict__ cnt64, float* __restrict__ tabG) {
    int i = blockIdx.x * blockDim.x + threadIdx.x;
    if (i < 10000) cnt64[i] = 0;
    else if (i < 24092) tabG[i - 10000] = 0.f;
}

// Fused: blocks [0,625): ONE u64 atomic per edge gives rank (hi 44) and
//        accumulates the weight sum (lo 44, 2^26 fixed point).
//        blocks [625,...): weight composition into tabG (independent work).
#define CNT_BLOCKS 625
#define WB_WAVES 6132   // 6000 table + 12 probs + 120 wt-repack
__global__ __launch_bounds__(256) void k_count(
        const int* __restrict__ ei, const float* __restrict__ w,
        u64* __restrict__ cnt64, int* __restrict__ rank,
        const float* __restrict__ Wz, const float* __restrict__ bz,
        const float* __restrict__ Wh, const float* __restrict__ bh,
        const float* __restrict__ Wlz, const float* __restrict__ blz,
        const float* __restrict__ Wlh, const float* __restrict__ blh,
        const float* __restrict__ att, const float* __restrict__ Whead,
        float* __restrict__ tabG) {
    int bid = blockIdx.x;
    int tid = threadIdx.x;
    if (bid < CNT_BLOCKS) {
        int e = bid * 256 + tid;
        if (e < NE) {
            int c = ei[NE + e];
            u64 fixed = (u64)(w[e] * WSCALE + 0.5f);
            u64 old = atomicAdd(&cnt64[c], (1ULL << 44) | fixed);
            rank[e] = (int)(old >> 44);
        }
        return;
    }
    int wid = (bid - CNT_BLOCKS) * 4 + (tid >> 6);
    int lane = tid & 63;
    if (wid >= WB_WAVES) return;

    if (wid < 6000) {
        const float* va;
        const float* vb;
        float scale, bias = 0.f;
        if (wid < 2400) {
            int f = wid / NC, d = wid % NC;
            va = Wz + f * NC; vb = Wlz + d * (2 * NC); scale = LOG2E;
        } else if (wid < 4800) {
            int j = wid - 2400;
            int f = j / NC, d = j % NC;
            va = Wh + f * NC; vb = Wlh + d * (2 * NC); scale = 2.0f * LOG2E;
        } else if (wid < 5400) {
            int d = wid - 4800;
            va = bz; vb = Wlz + d * (2 * NC); scale = LOG2E; bias = blz[d];
        } else {
            int d = wid - 5400;
            va = bh; vb = Wlh + d * (2 * NC); scale = 2.0f * LOG2E; bias = blh[d];
        }
        float s = 0.f;
        for (int c = lane; c < NC; c += 64) s = fmaf(va[c], vb[c], s);
#pragma unroll
        for (int off = 32; off > 0; off >>= 1) s += __shfl_down(s, off, 64);
        if (lane == 0) {
            float r = scale * (bias + s);
            if (wid < 2400) {
                int f = wid / NC, d = wid % NC;
                tabG[d * 4 + f] = r;
            } else if (wid < 4800) {
                int j = wid - 2400;
                int f = j / NC, d = j % NC;
                tabG[2560 + d * 4 + f] = r;
            } else if (wid < 5400) {
                tabG[5120 + (wid - 4800) * 2] = r;
            } else {
                tabG[5120 + (wid - 5400) * 2 + 1] = r;
            }
        }
    } else if (wid < 6012) {
        if (lane == 0) {
            int t = wid - 6000;
            float m = att[0];
            for (int k = 1; k < NT; ++k) m = fmaxf(m, att[k]);
            float ssum = 0.f;
            for (int k = 0; k < NT; ++k) ssum += __expf(att[k] - m);
            tabG[14080 + t] = __expf(att[t] - m) / ssum;
        }
    } else {
        int i = (wid - 6012) * 64 + lane;   // [0,7680)
        if (i < 7680) {
            int j = i & 3;
            int rest = i >> 2;          // [0,1920)
            int d = rest % NCP, q = rest / NCP;
            float v = (d < NC) ? Whead[(4 * q + j) * NC + d] : 0.f;
            tabG[6400 + i] = v;
        }
    }
}

// single-block exclusive scan of counts -> base; dis = rsqrt(1 + deg) decoded
// from the packed u64 (count in hi 44, weight-sum fp26 in lo 44).
#define SCAN_CHUNK 20
__global__ __launch_bounds__(256) void k_scan(const u64* __restrict__ cnt64,
                                              int* __restrict__ base,
                                              float* __restrict__ dis) {
    __shared__ int part[256];
    int t = threadIdx.x;
    int start = t * SCAN_CHUNK;
    int s = 0;
#pragma unroll
    for (int k = 0; k < SCAN_CHUNK; ++k) {
        int idx = start + k;
        if (idx < NN) s += (int)(cnt64[idx] >> 44);
    }
    part[t] = s;
    __syncthreads();
    for (int off = 1; off < 256; off <<= 1) {
        int v = (t >= off) ? part[t - off] : 0;
        __syncthreads();
        part[t] += v;
        __syncthreads();
    }
    int running = (t == 0) ? 0 : part[t - 1];
#pragma unroll
    for (int k = 0; k < SCAN_CHUNK; ++k) {
        int idx = start + k;
        if (idx < NN) {
            u64 v = cnt64[idx];
            base[idx] = running;
            running += (int)(v >> 44);
            float deg = (float)(v & MASK44) * (1.0f / WSCALE);
            dis[idx] = rsqrtf(1.0f + deg);
        }
    }
    if (t == 255) base[NN] = part[255];
}

// deterministic-position scatter of packed (src, weight): one 8B store
__global__ void k_scatter(const int* __restrict__ ei, const float* __restrict__ w,
                          const int* __restrict__ base, const int* __restrict__ rank,
                          int2* __restrict__ epak) {
    int e = blockIdx.x * blockDim.x + threadIdx.x;
    if (e < NE) {
        int2 p; p.x = ei[e]; p.y = __float_as_int(w[e]);
        epak[base[ei[NE + e]] + rank[e]] = p;
    }
}

// one 64-thread block per node:
// agg[n] = dn*(dn*x[n] + sum_j dis[s_j]*w_j*x[s_j])
__global__ __launch_bounds__(64) void k_gather(
        const float* __restrict__ x, const float* __restrict__ dis,
        const int2* __restrict__ epak, const int* __restrict__ base,
        float* __restrict__ agg) {
    int n = blockIdx.x;
    int lane = threadIdx.x;
    int b0 = base[n], b1 = base[n + 1];
    float dn = dis[n];
    float acc = 0.f;
    if (lane < FT) acc = dn * x[n * FT + lane];
    int j = b0;
    for (; j + 3 < b1; j += 4) {
        int2 p0 = epak[j], p1 = epak[j + 1], p2 = epak[j + 2], p3 = epak[j + 3];
        float n0 = dis[p0.x] * __int_as_float(p0.y);
        float n1 = dis[p1.x] * __int_as_float(p1.y);
        float n2 = dis[p2.x] * __int_as_float(p2.y);
        float n3 = dis[p3.x] * __int_as_float(p3.y);
        if (lane < FT) {
            acc += n0 * x[p0.x * FT + lane];
            acc += n1 * x[p1.x * FT + lane];
            acc += n2 * x[p2.x * FT + lane];
            acc += n3 * x[p3.x * FT + lane];
        }
    }
    for (; j < b1; ++j) {
        int2 p0 = epak[j];
        float n0 = dis[p0.x] * __int_as_float(p0.y);
        if (lane < FT) acc += n0 * x[p0.x * FT + lane];
    }
    if (lane < FT) agg[n * FT + lane] = dn * acc;
}

// Gate + attention + head. 1250 blocks x 4 waves; wave = node.
// n wave-uniform via readfirstlane -> agg row + probs live in SGPRs;
// lb(256,4) caps VGPR at 64 (demand ~50 with scalar A2 -> no spill, 16 w/CU).
__global__ __launch_bounds__(256, 4) void k_main(
        const float* __restrict__ agg, const float* __restrict__ tabG,
        const float* __restrict__ bhead, float* __restrict__ out) {
    __shared__ float red[4][NT][16];
    int tid = threadIdx.x;
    int wid = __builtin_amdgcn_readfirstlane(tid >> 6);
    int lane = tid & 63;
    int n = blockIdx.x * 4 + wid;   // uniform

    const float4* mz4 = (const float4*)tabG;
    const float4* mh4 = (const float4*)(tabG + 2560);
    const float2* bzh = (const float2*)(tabG + 5120);
    const float4* wt4 = (const float4*)(tabG + 6400);   // [q*640 + d]

    // wave-uniform agg row -> scalar loads (SGPR-resident)
    const v2f* ag2 = (const v2f*)(agg + n * FT);
    v2f A2[24];
#pragma unroll
    for (int i = 0; i < 24; ++i) A2[i] = ag2[i];

    v2f pp[6];
#pragma unroll
    for (int tp = 0; tp < 6; ++tp) { pp[tp].x = tabG[14080 + 2 * tp]; pp[tp].y = tabG[14080 + 2 * tp + 1]; }

    float outp[NT];
#pragma unroll
    for (int t = 0; t < NT; ++t) outp[t] = 0.f;

#pragma unroll
    for (int it = 0; it < 10; ++it) {
        int dd = it * 64 + lane;   // < 640, pad rows are zero -> r = 0

        float4 mzv = mz4[dd];
        float4 mhv = mh4[dd];
        float2 bb = bzh[dd];

        v2f hacc; hacc.x = 0.f; hacc.y = 0.f;
#pragma unroll
        for (int tp = 0; tp < 6; ++tp) {
            v2f u; u.x = bb.x; u.y = bb.x;
            v2f v; v.x = bb.y; v.y = bb.y;
            u += A2[0 * 6 + tp] * mzv.x;
            u += A2[1 * 6 + tp] * mzv.y;
            u += A2[2 * 6 + tp] * mzv.z;
            u += A2[3 * 6 + tp] * mzv.w;
            v += A2[0 * 6 + tp] * mhv.x;
            v += A2[1 * 6 + tp] * mhv.y;
            v += A2[2 * 6 + tp] * mhv.z;
            v += A2[3 * 6 + tp] * mhv.w;
            v2f eu; eu.x = exp2f(u.x); eu.y = exp2f(u.y);
            v2f ev; ev.x = exp2f(v.x); ev.y = exp2f(v.y);
            v2f den = (eu + 1.f) * (ev + 1.f);
            v2f rd; rd.x = __builtin_amdgcn_rcpf(den.x); rd.y = __builtin_amdgcn_rcpf(den.y);
            v2f num = pp[tp] * (ev - 1.f);
            hacc += num * rd;
        }
        float r = fmaxf(hacc.x + hacc.y, 0.f);

        float4 w0 = wt4[0 * NCP + dd], w1 = wt4[1 * NCP + dd], w2 = wt4[2 * NCP + dd];
        outp[0]  = fmaf(r, w0.x, outp[0]);   outp[1]  = fmaf(r, w0.y, outp[1]);
        outp[2]  = fmaf(r, w0.z, outp[2]);   outp[3]  = fmaf(r, w0.w, outp[3]);
        outp[4]  = fmaf(r, w1.x, outp[4]);   outp[5]  = fmaf(r, w1.y, outp[5]);
        outp[6]  = fmaf(r, w1.z, outp[6]);   outp[7]  = fmaf(r, w1.w, outp[7]);
        outp[8]  = fmaf(r, w2.x, outp[8]);   outp[9]  = fmaf(r, w2.y, outp[9]);
        outp[10] = fmaf(r, w2.z, outp[10]);  outp[11] = fmaf(r, w2.w, outp[11]);
    }

    // 2-step shuffle then 16-wide LDS transpose reduce (wave-private)
#pragma unroll
    for (int t = 0; t < NT; ++t) {
        float v = outp[t];
        v += __shfl_xor(v, 32, 64);
        v += __shfl_xor(v, 16, 64);
        if (lane < 16) red[wid][t][lane] = v;
    }
    if (lane < NT) {
        const float4* row = (const float4*)red[wid][lane];
        float4 a = row[0], b = row[1], c = row[2], d = row[3];
        float s = ((a.x + a.y) + (a.z + a.w)) + ((b.x + b.y) + (b.z + b.w))
                + ((c.x + c.y) + (c.z + c.w)) + ((d.x + d.y) + (d.z + d.w));
        out[n * NT + lane] = s + bhead[lane];
    }
}

extern "C" void kernel_launch(void* const* d_in, const int* in_sizes, int n_in,
                              void* d_out, int out_size, void* d_ws, size_t ws_size,
                              hipStream_t stream) {
    const float* x     = (const float*)d_in[0];
    const int*   ei    = (const int*)d_in[1];
    const float* ea    = (const float*)d_in[2];
    const float* Wz    = (const float*)d_in[3];
    const float* bz    = (const float*)d_in[4];
    const float* Wh    = (const float*)d_in[7];
    const float* bh    = (const float*)d_in[8];
    const float* Wlz   = (const float*)d_in[9];
    const float* blz   = (const float*)d_in[10];
    const float* Wlh   = (const float*)d_in[13];
    const float* blh   = (const float*)d_in[14];
    const float* att   = (const float*)d_in[15];
    const float* Whead = (const float*)d_in[16];
    const float* bhead = (const float*)d_in[17];
    float* out = (float*)d_out;

    float* ws    = (float*)d_ws;
    u64*   cnt64 = (u64*)ws;                // [0,10000) words
    int*   base  = (int*)(ws + 10000);      // [10000,15008)
    int*   rank  = (int*)(ws + 15008);
    int2*  epak  = (int2*)(ws + 175008);
    float* dis   = ws + 495008;
    float* agg   = ws + 500008;
    float* tabG  = ws + 740008;

    k_init<<<(24092 + 255) / 256, 256, 0, stream>>>((int*)cnt64, tabG);
    k_count<<<CNT_BLOCKS + (WB_WAVES + 3) / 4, 256, 0, stream>>>(
        ei, ea, cnt64, rank,
        Wz, bz, Wh, bh, Wlz, blz, Wlh, blh, att, Whead, tabG);
    k_scan<<<1, 256, 0, stream>>>(cnt64, base, dis);
    k_scatter<<<(NE + 255) / 256, 256, 0, stream>>>(ei, ea, base, rank, epak);
    k_gather<<<NN, 64, 0, stream>>>(x, dis, epak, base, agg);
    k_main<<<NN / 4, 256, 0, stream>>>(agg, tabG, bhead, out);
}

// Round 19
// 74.288 us; speedup vs baseline: 1.1062x; 1.0969x over previous
//
#include <hip/hip_runtime.h>

#define NN 5000
#define NF 4
#define NT 12
#define NC 600
#define NCP 640   // padded d-extent (zero pad -> r=0, no predication)
#define NE 160000
#define FT 48   // NF*NT
#define LOG2E 1.4426950408889634f

typedef float v2f __attribute__((ext_vector_type(2)));

// ws layout (float offsets):
//   cnt   [0,     5000)    int   (zeroed by k_init)
//   base  [5000, 10001)    int   (pad to 10008)
//   rank  [10008,170008)   int
//   epak  [170008,490008)  int2 (src, w-bits) per bucketed edge
//   dis   [490008,495008)
//   tabG  [495008,509100)  packed PADDED tables (zeroed by k_init):
//     mz4   [0,2560)       float4[640] (LOG2E-scaled)
//     mh4   [2560,5120)    float4[640] (2*LOG2E-scaled)
//     bzh   [5120,6400)    float2[640] (betaz,betah)
//     wt    [6400,14080)   float4[3][640]: wt[q][d][j] = Whead[4q+j][d]
//     probs [14080,14092)

// zero cnt (5000 words) and tabG (14092 words)
__global__ void k_init(int* __restrict__ cnt, float* __restrict__ tabG) {
    int i = blockIdx.x * blockDim.x + threadIdx.x;
    if (i < 5000) cnt[i] = 0;
    else if (i < 19092) tabG[i - 5000] = 0.f;
}

// Fused: blocks [0,625) rank histogram (int atomic only);
//        blocks [625,...) weight composition into tabG (independent work).
#define CNT_BLOCKS 625
#define WB_WAVES 6132   // 6000 table + 12 probs + 120 wt-repack
__global__ __launch_bounds__(256) void k_count(
        const int* __restrict__ ei,
        int* __restrict__ cnt, int* __restrict__ rank,
        const float* __restrict__ Wz, const float* __restrict__ bz,
        const float* __restrict__ Wh, const float* __restrict__ bh,
        const float* __restrict__ Wlz, const float* __restrict__ blz,
        const float* __restrict__ Wlh, const float* __restrict__ blh,
        const float* __restrict__ att, const float* __restrict__ Whead,
        float* __restrict__ tabG) {
    int bid = blockIdx.x;
    int tid = threadIdx.x;
    if (bid < CNT_BLOCKS) {
        int e = bid * 256 + tid;
        if (e < NE) rank[e] = atomicAdd(&cnt[ei[NE + e]], 1);
        return;
    }
    int wid = (bid - CNT_BLOCKS) * 4 + (tid >> 6);
    int lane = tid & 63;
    if (wid >= WB_WAVES) return;

    if (wid < 6000) {
        const float* va;
        const float* vb;
        float scale, bias = 0.f;
        if (wid < 2400) {
            int f = wid / NC, d = wid % NC;
            va = Wz + f * NC; vb = Wlz + d * (2 * NC); scale = LOG2E;
        } else if (wid < 4800) {
            int j = wid - 2400;
            int f = j / NC, d = j % NC;
            va = Wh + f * NC; vb = Wlh + d * (2 * NC); scale = 2.0f * LOG2E;
        } else if (wid < 5400) {
            int d = wid - 4800;
            va = bz; vb = Wlz + d * (2 * NC); scale = LOG2E; bias = blz[d];
        } else {
            int d = wid - 5400;
            va = bh; vb = Wlh + d * (2 * NC); scale = 2.0f * LOG2E; bias = blh[d];
        }
        float s = 0.f;
        for (int c = lane; c < NC; c += 64) s = fmaf(va[c], vb[c], s);
#pragma unroll
        for (int off = 32; off > 0; off >>= 1) s += __shfl_down(s, off, 64);
        if (lane == 0) {
            float r = scale * (bias + s);
            if (wid < 2400) {
                int f = wid / NC, d = wid % NC;
                tabG[d * 4 + f] = r;
            } else if (wid < 4800) {
                int j = wid - 2400;
                int f = j / NC, d = j % NC;
                tabG[2560 + d * 4 + f] = r;
            } else if (wid < 5400) {
                tabG[5120 + (wid - 4800) * 2] = r;
            } else {
                tabG[5120 + (wid - 5400) * 2 + 1] = r;
            }
        }
    } else if (wid < 6012) {
        if (lane == 0) {
            int t = wid - 6000;
            float m = att[0];
            for (int k = 1; k < NT; ++k) m = fmaxf(m, att[k]);
            float ssum = 0.f;
            for (int k = 0; k < NT; ++k) ssum += __expf(att[k] - m);
            tabG[14080 + t] = __expf(att[t] - m) / ssum;
        }
    } else {
        int i = (wid - 6012) * 64 + lane;   // [0,7680)
        if (i < 7680) {
            int j = i & 3;
            int rest = i >> 2;          // [0,1920)
            int d = rest % NCP, q = rest / NCP;
            float v = (d < NC) ? Whead[(4 * q + j) * NC + d] : 0.f;
            tabG[6400 + i] = v;
        }
    }
}

// single-block exclusive scan of cnt -> base
#define SCAN_CHUNK 20
__global__ __launch_bounds__(256) void k_scan(const int* __restrict__ cnt,
                                              int* __restrict__ base) {
    __shared__ int part[256];
    int t = threadIdx.x;
    int start = t * SCAN_CHUNK;
    int s = 0;
#pragma unroll
    for (int k = 0; k < SCAN_CHUNK; ++k) {
        int idx = start + k;
        if (idx < NN) s += cnt[idx];
    }
    part[t] = s;
    __syncthreads();
    for (int off = 1; off < 256; off <<= 1) {
        int v = (t >= off) ? part[t - off] : 0;
        __syncthreads();
        part[t] += v;
        __syncthreads();
    }
    int running = (t == 0) ? 0 : part[t - 1];
#pragma unroll
    for (int k = 0; k < SCAN_CHUNK; ++k) {
        int idx = start + k;
        if (idx < NN) {
            base[idx] = running;
            running += cnt[idx];
        }
    }
    if (t == 255) base[NN] = part[255];
}

// deterministic-position scatter of packed (src, weight): one 8B store
__global__ void k_scatter(const int* __restrict__ ei, const float* __restrict__ w,
                          const int* __restrict__ base, const int* __restrict__ rank,
                          int2* __restrict__ epak) {
    int e = blockIdx.x * blockDim.x + threadIdx.x;
    if (e < NE) {
        int2 p; p.x = ei[e]; p.y = __float_as_int(w[e]);
        epak[base[ei[NE + e]] + rank[e]] = p;
    }
}

// per-node degree from packed edges (sequential reads), dis = rsqrt(1+deg)
__global__ __launch_bounds__(64) void k_deg_dis(const int2* __restrict__ epak,
                                                const int* __restrict__ base,
                                                float* __restrict__ dis) {
    int n = blockIdx.x;
    int lane = threadIdx.x;
    int b0 = base[n], b1 = base[n + 1];
    float s = 0.f;
    for (int j = b0 + lane; j < b1; j += 64) s += __int_as_float(epak[j].y);
#pragma unroll
    for (int off = 32; off > 0; off >>= 1) s += __shfl_down(s, off, 64);
    if (lane == 0) dis[n] = rsqrtf(1.0f + s);
}

// FUSED gather + gate + attention + head. 1250 blocks x 4 waves; wave = node.
// Phase 1 (gather): lane ft holds agg[n][ft] in acc (R14 k_gather body).
// Phase 2 (gate): agg row broadcast to SGPRs via v_readlane (literal lanes) --
// no LDS, no global round-trip, A2 scalar => no VGPR spill at the lb(256,4) cap.
__global__ __launch_bounds__(256, 4) void k_node(
        const float* __restrict__ x, const float* __restrict__ dis,
        const int2* __restrict__ epak, const int* __restrict__ base,
        const float* __restrict__ tabG,
        const float* __restrict__ bhead, float* __restrict__ out) {
    __shared__ float red[4][NT][16];
    int tid = threadIdx.x;
    int wid = __builtin_amdgcn_readfirstlane(tid >> 6);
    int lane = tid & 63;
    int n = blockIdx.x * 4 + wid;   // uniform

    // ---- phase 1: gather (same memory pattern as R14 k_gather) ----
    int b0 = base[n], b1 = base[n + 1];
    float dn = dis[n];
    float acc = 0.f;
    if (lane < FT) acc = dn * x[n * FT + lane];
    int j = b0;
    for (; j + 3 < b1; j += 4) {
        int2 p0 = epak[j], p1 = epak[j + 1], p2 = epak[j + 2], p3 = epak[j + 3];
        float n0 = dis[p0.x] * __int_as_float(p0.y);
        float n1 = dis[p1.x] * __int_as_float(p1.y);
        float n2 = dis[p2.x] * __int_as_float(p2.y);
        float n3 = dis[p3.x] * __int_as_float(p3.y);
        if (lane < FT) {
            acc += n0 * x[p0.x * FT + lane];
            acc += n1 * x[p1.x * FT + lane];
            acc += n2 * x[p2.x * FT + lane];
            acc += n3 * x[p3.x * FT + lane];
        }
    }
    for (; j < b1; ++j) {
        int2 p0 = epak[j];
        float n0 = dis[p0.x] * __int_as_float(p0.y);
        if (lane < FT) acc += n0 * x[p0.x * FT + lane];
    }
    acc *= dn;   // lane ft (ft<48) now holds agg[n][ft]

    // ---- broadcast agg row to wave-uniform scalars (SGPRs) ----
    v2f A2[24];
#pragma unroll
    for (int i = 0; i < 24; ++i) {
        A2[i].x = __int_as_float(__builtin_amdgcn_readlane(__float_as_int(acc), 2 * i));
        A2[i].y = __int_as_float(__builtin_amdgcn_readlane(__float_as_int(acc), 2 * i + 1));
    }

    // ---- phase 2: gate + attention + head (R14 k_main body) ----
    const float4* mz4 = (const float4*)tabG;
    const float4* mh4 = (const float4*)(tabG + 2560);
    const float2* bzh = (const float2*)(tabG + 5120);
    const float4* wt4 = (const float4*)(tabG + 6400);   // [q*640 + d]

    v2f pp[6];
#pragma unroll
    for (int tp = 0; tp < 6; ++tp) { pp[tp].x = tabG[14080 + 2 * tp]; pp[tp].y = tabG[14080 + 2 * tp + 1]; }

    float outp[NT];
#pragma unroll
    for (int t = 0; t < NT; ++t) outp[t] = 0.f;

#pragma unroll
    for (int it = 0; it < 10; ++it) {
        int dd = it * 64 + lane;   // < 640, pad rows are zero -> r = 0

        float4 mzv = mz4[dd];
        float4 mhv = mh4[dd];
        float2 bb = bzh[dd];

        v2f hacc; hacc.x = 0.f; hacc.y = 0.f;
#pragma unroll
        for (int tp = 0; tp < 6; ++tp) {
            v2f u; u.x = bb.x; u.y = bb.x;
            v2f v; v.x = bb.y; v.y = bb.y;
            u += A2[0 * 6 + tp] * mzv.x;
            u += A2[1 * 6 + tp] * mzv.y;
            u += A2[2 * 6 + tp] * mzv.z;
            u += A2[3 * 6 + tp] * mzv.w;
            v += A2[0 * 6 + tp] * mhv.x;
            v += A2[1 * 6 + tp] * mhv.y;
            v += A2[2 * 6 + tp] * mhv.z;
            v += A2[3 * 6 + tp] * mhv.w;
            v2f eu; eu.x = exp2f(u.x); eu.y = exp2f(u.y);
            v2f ev; ev.x = exp2f(v.x); ev.y = exp2f(v.y);
            v2f den = (eu + 1.f) * (ev + 1.f);
            v2f rd; rd.x = __builtin_amdgcn_rcpf(den.x); rd.y = __builtin_amdgcn_rcpf(den.y);
            v2f num = pp[tp] * (ev - 1.f);
            hacc += num * rd;
        }
        float r = fmaxf(hacc.x + hacc.y, 0.f);

        float4 w0 = wt4[0 * NCP + dd], w1 = wt4[1 * NCP + dd], w2 = wt4[2 * NCP + dd];
        outp[0]  = fmaf(r, w0.x, outp[0]);   outp[1]  = fmaf(r, w0.y, outp[1]);
        outp[2]  = fmaf(r, w0.z, outp[2]);   outp[3]  = fmaf(r, w0.w, outp[3]);
        outp[4]  = fmaf(r, w1.x, outp[4]);   outp[5]  = fmaf(r, w1.y, outp[5]);
        outp[6]  = fmaf(r, w1.z, outp[6]);   outp[7]  = fmaf(r, w1.w, outp[7]);
        outp[8]  = fmaf(r, w2.x, outp[8]);   outp[9]  = fmaf(r, w2.y, outp[9]);
        outp[10] = fmaf(r, w2.z, outp[10]);  outp[11] = fmaf(r, w2.w, outp[11]);
    }

    // 2-step shuffle then 16-wide LDS transpose reduce (wave-private)
#pragma unroll
    for (int t = 0; t < NT; ++t) {
        float v = outp[t];
        v += __shfl_xor(v, 32, 64);
        v += __shfl_xor(v, 16, 64);
        if (lane < 16) red[wid][t][lane] = v;
    }
    if (lane < NT) {
        const float4* row = (const float4*)red[wid][lane];
        float4 a = row[0], b = row[1], c = row[2], d = row[3];
        float s = ((a.x + a.y) + (a.z + a.w)) + ((b.x + b.y) + (b.z + b.w))
                + ((c.x + c.y) + (c.z + c.w)) + ((d.x + d.y) + (d.z + d.w));
        out[n * NT + lane] = s + bhead[lane];
    }
}

extern "C" void kernel_launch(void* const* d_in, const int* in_sizes, int n_in,
                              void* d_out, int out_size, void* d_ws, size_t ws_size,
                              hipStream_t stream) {
    const float* x     = (const float*)d_in[0];
    const int*   ei    = (const int*)d_in[1];
    const float* ea    = (const float*)d_in[2];
    const float* Wz    = (const float*)d_in[3];
    const float* bz    = (const float*)d_in[4];
    const float* Wh    = (const float*)d_in[7];
    const float* bh    = (const float*)d_in[8];
    const float* Wlz   = (const float*)d_in[9];
    const float* blz   = (const float*)d_in[10];
    const float* Wlh   = (const float*)d_in[13];
    const float* blh   = (const float*)d_in[14];
    const float* att   = (const float*)d_in[15];
    const float* Whead = (const float*)d_in[16];
    const float* bhead = (const float*)d_in[17];
    float* out = (float*)d_out;

    float* ws   = (float*)d_ws;
    int*   cnt  = (int*)ws;                 // [0,5000)
    int*   base = (int*)(ws + 5000);        // [5000,10008)
    int*   rank = (int*)(ws + 10008);
    int2*  epak = (int2*)(ws + 170008);
    float* dis  = ws + 490008;
    float* tabG = ws + 495008;

    k_init<<<(19092 + 255) / 256, 256, 0, stream>>>(cnt, tabG);
    k_count<<<CNT_BLOCKS + (WB_WAVES + 3) / 4, 256, 0, stream>>>(
        ei, cnt, rank,
        Wz, bz, Wh, bh, Wlz, blz, Wlh, blh, att, Whead, tabG);
    k_scan<<<1, 256, 0, stream>>>(cnt, base);
    k_scatter<<<(NE + 255) / 256, 256, 0, stream>>>(ei, ea, base, rank, epak);
    k_deg_dis<<<NN, 64, 0, stream>>>(epak, base, dis);
    k_node<<<NN / 4, 256, 0, stream>>>(x, dis, epak, base, tabG, bhead, out);
}

// Round 20
// 73.520 us; speedup vs baseline: 1.1178x; 1.0104x over previous
//
#include <hip/hip_runtime.h>

#define NN 5000
#define NF 4
#define NT 12
#define NC 600
#define NCP 640   // padded d-extent (zero pad -> r=0, no predication)
#define NE 160000
#define FT 48   // NF*NT
#define LOG2E 1.4426950408889634f

typedef float v2f __attribute__((ext_vector_type(2)));

// ws layout (float offsets):
//   cnt   [0,     5000)    int   (zeroed by k_init)
//   base  [5000, 10001)    int   (pad to 10008)
//   rank  [10008,170008)   int
//   epak  [170008,490008)  int2 (src, w-bits) per bucketed edge
//   dis   [490008,495008)
//   tabG  [495008,509100)  packed PADDED tables (zeroed by k_init):
//     mz4   [0,2560)       float4[640] (LOG2E-scaled)
//     mh4   [2560,5120)    float4[640] (2*LOG2E-scaled)
//     bzh   [5120,6400)    float2[640] (betaz,betah)
//     wt    [6400,14080)   float4[3][640]: wt[q][d][j] = Whead[4q+j][d]
//     probs [14080,14092)

// zero cnt (5000 words) and tabG (14092 words)
__global__ void k_init(int* __restrict__ cnt, float* __restrict__ tabG) {
    int i = blockIdx.x * blockDim.x + threadIdx.x;
    if (i < 5000) cnt[i] = 0;
    else if (i < 19092) tabG[i - 5000] = 0.f;
}

// Fused: blocks [0,625) rank histogram (int atomic only);
//        blocks [625,...) weight composition into tabG (independent work).
#define CNT_BLOCKS 625
#define WB_WAVES 6132   // 6000 table + 12 probs + 120 wt-repack
__global__ __launch_bounds__(256) void k_count(
        const int* __restrict__ ei,
        int* __restrict__ cnt, int* __restrict__ rank,
        const float* __restrict__ Wz, const float* __restrict__ bz,
        const float* __restrict__ Wh, const float* __restrict__ bh,
        const float* __restrict__ Wlz, const float* __restrict__ blz,
        const float* __restrict__ Wlh, const float* __restrict__ blh,
        const float* __restrict__ att, const float* __restrict__ Whead,
        float* __restrict__ tabG) {
    int bid = blockIdx.x;
    int tid = threadIdx.x;
    if (bid < CNT_BLOCKS) {
        int e = bid * 256 + tid;
        if (e < NE) rank[e] = atomicAdd(&cnt[ei[NE + e]], 1);
        return;
    }
    int wid = (bid - CNT_BLOCKS) * 4 + (tid >> 6);
    int lane = tid & 63;
    if (wid >= WB_WAVES) return;

    if (wid < 6000) {
        const float* va;
        const float* vb;
        float scale, bias = 0.f;
        if (wid < 2400) {
            int f = wid / NC, d = wid % NC;
            va = Wz + f * NC; vb = Wlz + d * (2 * NC); scale = LOG2E;
        } else if (wid < 4800) {
            int j = wid - 2400;
            int f = j / NC, d = j % NC;
            va = Wh + f * NC; vb = Wlh + d * (2 * NC); scale = 2.0f * LOG2E;
        } else if (wid < 5400) {
            int d = wid - 4800;
            va = bz; vb = Wlz + d * (2 * NC); scale = LOG2E; bias = blz[d];
        } else {
            int d = wid - 5400;
            va = bh; vb = Wlh + d * (2 * NC); scale = 2.0f * LOG2E; bias = blh[d];
        }
        float s = 0.f;
        for (int c = lane; c < NC; c += 64) s = fmaf(va[c], vb[c], s);
#pragma unroll
        for (int off = 32; off > 0; off >>= 1) s += __shfl_down(s, off, 64);
        if (lane == 0) {
            float r = scale * (bias + s);
            if (wid < 2400) {
                int f = wid / NC, d = wid % NC;
                tabG[d * 4 + f] = r;
            } else if (wid < 4800) {
                int j = wid - 2400;
                int f = j / NC, d = j % NC;
                tabG[2560 + d * 4 + f] = r;
            } else if (wid < 5400) {
                tabG[5120 + (wid - 4800) * 2] = r;
            } else {
                tabG[5120 + (wid - 5400) * 2 + 1] = r;
            }
        }
    } else if (wid < 6012) {
        if (lane == 0) {
            int t = wid - 6000;
            float m = att[0];
            for (int k = 1; k < NT; ++k) m = fmaxf(m, att[k]);
            float ssum = 0.f;
            for (int k = 0; k < NT; ++k) ssum += __expf(att[k] - m);
            tabG[14080 + t] = __expf(att[t] - m) / ssum;
        }
    } else {
        int i = (wid - 6012) * 64 + lane;   // [0,7680)
        if (i < 7680) {
            int j = i & 3;
            int rest = i >> 2;          // [0,1920)
            int d = rest % NCP, q = rest / NCP;
            float v = (d < NC) ? Whead[(4 * q + j) * NC + d] : 0.f;
            tabG[6400 + i] = v;
        }
    }
}

// single-block exclusive scan of cnt -> base
#define SCAN_CHUNK 20
__global__ __launch_bounds__(256) void k_scan(const int* __restrict__ cnt,
                                              int* __restrict__ base) {
    __shared__ int part[256];
    int t = threadIdx.x;
    int start = t * SCAN_CHUNK;
    int s = 0;
#pragma unroll
    for (int k = 0; k < SCAN_CHUNK; ++k) {
        int idx = start + k;
        if (idx < NN) s += cnt[idx];
    }
    part[t] = s;
    __syncthreads();
    for (int off = 1; off < 256; off <<= 1) {
        int v = (t >= off) ? part[t - off] : 0;
        __syncthreads();
        part[t] += v;
        __syncthreads();
    }
    int running = (t == 0) ? 0 : part[t - 1];
#pragma unroll
    for (int k = 0; k < SCAN_CHUNK; ++k) {
        int idx = start + k;
        if (idx < NN) {
            base[idx] = running;
            running += cnt[idx];
        }
    }
    if (t == 255) base[NN] = part[255];
}

// deterministic-position scatter of packed (src, weight): one 8B store
__global__ void k_scatter(const int* __restrict__ ei, const float* __restrict__ w,
                          const int* __restrict__ base, const int* __restrict__ rank,
                          int2* __restrict__ epak) {
    int e = blockIdx.x * blockDim.x + threadIdx.x;
    if (e < NE) {
        int2 p; p.x = ei[e]; p.y = __float_as_int(w[e]);
        epak[base[ei[NE + e]] + rank[e]] = p;
    }
}

// per-node degree from packed edges (sequential reads), dis = rsqrt(1+deg)
__global__ __launch_bounds__(64) void k_deg_dis(const int2* __restrict__ epak,
                                                const int* __restrict__ base,
                                                float* __restrict__ dis) {
    int n = blockIdx.x;
    int lane = threadIdx.x;
    int b0 = base[n], b1 = base[n + 1];
    float s = 0.f;
    for (int j = b0 + lane; j < b1; j += 64) s += __int_as_float(epak[j].y);
#pragma unroll
    for (int off = 32; off > 0; off >>= 1) s += __shfl_down(s, off, 64);
    if (lane == 0) dis[n] = rsqrtf(1.0f + s);
}

// FUSED gather + gate + attention + head. 1250 blocks x 4 waves; wave = node.
// Phase 1 (gather): lane ft holds agg[n][ft] in acc (R14 k_gather body).
// Phase 2 (gate): agg row broadcast to SGPRs via v_readlane (literal lanes).
// lb(256,3): 84-VGPR budget -- enough for the fused gather+gate union, no
// scratch spill (R19's lb(256,4)=64 spilled ~14 B/thread -> 4.3 MB WRITE).
__global__ __launch_bounds__(256, 3) void k_node(
        const float* __restrict__ x, const float* __restrict__ dis,
        const int2* __restrict__ epak, const int* __restrict__ base,
        const float* __restrict__ tabG,
        const float* __restrict__ bhead, float* __restrict__ out) {
    __shared__ float red[4][NT][16];
    int tid = threadIdx.x;
    int wid = __builtin_amdgcn_readfirstlane(tid >> 6);
    int lane = tid & 63;
    int n = blockIdx.x * 4 + wid;   // uniform

    // ---- phase 1: gather (same memory pattern as R14 k_gather) ----
    int b0 = base[n], b1 = base[n + 1];
    float dn = dis[n];
    float acc = 0.f;
    if (lane < FT) acc = dn * x[n * FT + lane];
    int j = b0;
    for (; j + 3 < b1; j += 4) {
        int2 p0 = epak[j], p1 = epak[j + 1], p2 = epak[j + 2], p3 = epak[j + 3];
        float n0 = dis[p0.x] * __int_as_float(p0.y);
        float n1 = dis[p1.x] * __int_as_float(p1.y);
        float n2 = dis[p2.x] * __int_as_float(p2.y);
        float n3 = dis[p3.x] * __int_as_float(p3.y);
        if (lane < FT) {
            acc += n0 * x[p0.x * FT + lane];
            acc += n1 * x[p1.x * FT + lane];
            acc += n2 * x[p2.x * FT + lane];
            acc += n3 * x[p3.x * FT + lane];
        }
    }
    for (; j < b1; ++j) {
        int2 p0 = epak[j];
        float n0 = dis[p0.x] * __int_as_float(p0.y);
        if (lane < FT) acc += n0 * x[p0.x * FT + lane];
    }
    acc *= dn;   // lane ft (ft<48) now holds agg[n][ft]

    // ---- broadcast agg row to wave-uniform scalars (SGPRs) ----
    v2f A2[24];
#pragma unroll
    for (int i = 0; i < 24; ++i) {
        A2[i].x = __int_as_float(__builtin_amdgcn_readlane(__float_as_int(acc), 2 * i));
        A2[i].y = __int_as_float(__builtin_amdgcn_readlane(__float_as_int(acc), 2 * i + 1));
    }

    // ---- phase 2: gate + attention + head (R14 k_main body) ----
    const float4* mz4 = (const float4*)tabG;
    const float4* mh4 = (const float4*)(tabG + 2560);
    const float2* bzh = (const float2*)(tabG + 5120);
    const float4* wt4 = (const float4*)(tabG + 6400);   // [q*640 + d]

    v2f pp[6];
#pragma unroll
    for (int tp = 0; tp < 6; ++tp) { pp[tp].x = tabG[14080 + 2 * tp]; pp[tp].y = tabG[14080 + 2 * tp + 1]; }

    float outp[NT];
#pragma unroll
    for (int t = 0; t < NT; ++t) outp[t] = 0.f;

#pragma unroll
    for (int it = 0; it < 10; ++it) {
        int dd = it * 64 + lane;   // < 640, pad rows are zero -> r = 0

        float4 mzv = mz4[dd];
        float4 mhv = mh4[dd];
        float2 bb = bzh[dd];

        v2f hacc; hacc.x = 0.f; hacc.y = 0.f;
#pragma unroll
        for (int tp = 0; tp < 6; ++tp) {
            v2f u; u.x = bb.x; u.y = bb.x;
            v2f v; v.x = bb.y; v.y = bb.y;
            u += A2[0 * 6 + tp] * mzv.x;
            u += A2[1 * 6 + tp] * mzv.y;
            u += A2[2 * 6 + tp] * mzv.z;
            u += A2[3 * 6 + tp] * mzv.w;
            v += A2[0 * 6 + tp] * mhv.x;
            v += A2[1 * 6 + tp] * mhv.y;
            v += A2[2 * 6 + tp] * mhv.z;
            v += A2[3 * 6 + tp] * mhv.w;
            v2f eu; eu.x = exp2f(u.x); eu.y = exp2f(u.y);
            v2f ev; ev.x = exp2f(v.x); ev.y = exp2f(v.y);
            v2f den = (eu + 1.f) * (ev + 1.f);
            v2f rd; rd.x = __builtin_amdgcn_rcpf(den.x); rd.y = __builtin_amdgcn_rcpf(den.y);
            v2f num = pp[tp] * (ev - 1.f);
            hacc += num * rd;
        }
        float r = fmaxf(hacc.x + hacc.y, 0.f);

        float4 w0 = wt4[0 * NCP + dd], w1 = wt4[1 * NCP + dd], w2 = wt4[2 * NCP + dd];
        outp[0]  = fmaf(r, w0.x, outp[0]);   outp[1]  = fmaf(r, w0.y, outp[1]);
        outp[2]  = fmaf(r, w0.z, outp[2]);   outp[3]  = fmaf(r, w0.w, outp[3]);
        outp[4]  = fmaf(r, w1.x, outp[4]);   outp[5]  = fmaf(r, w1.y, outp[5]);
        outp[6]  = fmaf(r, w1.z, outp[6]);   outp[7]  = fmaf(r, w1.w, outp[7]);
        outp[8]  = fmaf(r, w2.x, outp[8]);   outp[9]  = fmaf(r, w2.y, outp[9]);
        outp[10] = fmaf(r, w2.z, outp[10]);  outp[11] = fmaf(r, w2.w, outp[11]);
    }

    // 2-step shuffle then 16-wide LDS transpose reduce (wave-private)
#pragma unroll
    for (int t = 0; t < NT; ++t) {
        float v = outp[t];
        v += __shfl_xor(v, 32, 64);
        v += __shfl_xor(v, 16, 64);
        if (lane < 16) red[wid][t][lane] = v;
    }
    if (lane < NT) {
        const float4* row = (const float4*)red[wid][lane];
        float4 a = row[0], b = row[1], c = row[2], d = row[3];
        float s = ((a.x + a.y) + (a.z + a.w)) + ((b.x + b.y) + (b.z + b.w))
                + ((c.x + c.y) + (c.z + c.w)) + ((d.x + d.y) + (d.z + d.w));
        out[n * NT + lane] = s + bhead[lane];
    }
}

extern "C" void kernel_launch(void* const* d_in, const int* in_sizes, int n_in,
                              void* d_out, int out_size, void* d_ws, size_t ws_size,
                              hipStream_t stream) {
    const float* x     = (const float*)d_in[0];
    const int*   ei    = (const int*)d_in[1];
    const float* ea    = (const float*)d_in[2];
    const float* Wz    = (const float*)d_in[3];
    const float* bz    = (const float*)d_in[4];
    const float* Wh    = (const float*)d_in[7];
    const float* bh    = (const float*)d_in[8];
    const float* Wlz   = (const float*)d_in[9];
    const float* blz   = (const float*)d_in[10];
    const float* Wlh   = (const float*)d_in[13];
    const float* blh   = (const float*)d_in[14];
    const float* att   = (const float*)d_in[15];
    const float* Whead = (const float*)d_in[16];
    const float* bhead = (const float*)d_in[17];
    float* out = (float*)d_out;

    float* ws   = (float*)d_ws;
    int*   cnt  = (int*)ws;                 // [0,5000)
    int*   base = (int*)(ws + 5000);        // [5000,10008)
    int*   rank = (int*)(ws + 10008);
    int2*  epak = (int2*)(ws + 170008);
    float* dis  = ws + 490008;
    float* tabG = ws + 495008;

    k_init<<<(19092 + 255) / 256, 256, 0, stream>>>(cnt, tabG);
    k_count<<<CNT_BLOCKS + (WB_WAVES + 3) / 4, 256, 0, stream>>>(
        ei, cnt, rank,
        Wz, bz, Wh, bh, Wlz, blz, Wlh, blh, att, Whead, tabG);
    k_scan<<<1, 256, 0, stream>>>(cnt, base);
    k_scatter<<<(NE + 255) / 256, 256, 0, stream>>>(ei, ea, base, rank, epak);
    k_deg_dis<<<NN, 64, 0, stream>>>(epak, base, dis);
    k_node<<<NN / 4, 256, 0, stream>>>(x, dis, epak, base, tabG, bhead, out);
}